// Round 1
// baseline (2505.542 us; speedup 1.0000x reference)
//
#include <hip/hip_runtime.h>
#include <stdint.h>

#define NB   16    // batches
#define WPB  16    // workgroups per batch
#define NTHR 512   // threads per workgroup (8 waves)
#define PPT  16    // points per thread = 131072 / (WPB*NTHR)

// JAX Threefry-2x32 (20 rounds), exact.
__device__ __forceinline__ void tf2x32(uint32_t k0, uint32_t k1,
                                       uint32_t x0, uint32_t x1,
                                       uint32_t &y0, uint32_t &y1) {
  uint32_t ks2 = k0 ^ k1 ^ 0x1BD11BDAu;
  uint32_t v0 = x0 + k0, v1 = x1 + k1;
#define TFR(r) { v0 += v1; v1 = (v1 << (r)) | (v1 >> (32 - (r))); v1 ^= v0; }
  TFR(13) TFR(15) TFR(26) TFR(6)   v0 += k1;  v1 += ks2 + 1u;
  TFR(17) TFR(29) TFR(16) TFR(24)  v0 += ks2; v1 += k0 + 2u;
  TFR(13) TFR(15) TFR(26) TFR(6)   v0 += k0;  v1 += k1 + 3u;
  TFR(17) TFR(29) TFR(16) TFR(24)  v0 += k1;  v1 += ks2 + 4u;
  TFR(13) TFR(15) TFR(26) TFR(6)   v0 += ks2; v1 += k0 + 5u;
#undef TFR
  y0 = v0; y1 = v1;
}

__global__ __launch_bounds__(NTHR, 4)
void FPSampler_42099269435595_kernel(const float* __restrict__ xyz,
                                     const int* __restrict__ npoint_ptr,
                                     float* __restrict__ out,
                                     unsigned long long* __restrict__ slots,
                                     int N) {
  const int blk  = blockIdx.x;
  const int b    = blk >> 4;          // batch
  const int w    = blk & (WPB - 1);   // wg within batch
  const int tid  = threadIdx.x;
  const int wave = tid >> 6;
  const int lane = tid & 63;
  const int npoint = npoint_ptr[0];

  const float* __restrict__ xb = xyz + (size_t)b * N * 3;
  const int pts_per_wg = N / WPB;     // 8192
  const int p0 = w * pts_per_wg + tid;

  // register-resident point slice + running min-distance
  float px[PPT], py[PPT], pz[PPT], dist[PPT];
#pragma unroll
  for (int k = 0; k < PPT; ++k) {
    size_t p = (size_t)(p0 + k * NTHR);
    px[k] = xb[3 * p + 0];
    py[k] = xb[3 * p + 1];
    pz[k] = xb[3 * p + 2];
    dist[k] = 1e10f;
  }

  // start = randint(fold_in(key(0),1),(16,),0,2^17)  (threefry, partitionable)
  uint32_t fk0, fk1, s0, s1, r0, r1;
  tf2x32(0u, 0u, 0u, 1u, fk0, fk1);          // fold_in(key(0), 1)
  tf2x32(fk0, fk1, 0u, 1u, s0, s1);          // split(key)[1]
  tf2x32(s0, s1, 0u, (uint32_t)b, r0, r1);   // random_bits element b
  uint32_t far = (r0 ^ r1) & 0x1FFFFu;       // % 131072 (span = 2^17)

  __shared__ unsigned long long lds_red[NTHR / 64];
  __shared__ unsigned long long lds_win;

  float* out_xyz = out;                          // (B, npoint, 3)
  float* out_idx = out + (size_t)NB * npoint * 3; // (B, npoint) as float

  for (int i = 0; i < npoint; ++i) {
    float cx = xb[3 * (size_t)far + 0];
    float cy = xb[3 * (size_t)far + 1];
    float cz = xb[3 * (size_t)far + 2];
    if (w == 0 && tid == 0) {
      size_t o = (size_t)b * npoint + i;
      out_xyz[3 * o + 0] = cx;
      out_xyz[3 * o + 1] = cy;
      out_xyz[3 * o + 2] = cz;
      out_idx[o] = (float)far;     // scan emits farthest BEFORE update
    }
    if (i == npoint - 1) break;

    float best = -1.0f;
    uint32_t bidx = 0;
#pragma unroll
    for (int k = 0; k < PPT; ++k) {
#pragma clang fp contract(off)
      float dx = px[k] - cx, dy = py[k] - cy, dz = pz[k] - cz;
      float d = (dx * dx + dy * dy) + dz * dz;  // match XLA: no FMA contraction
      float nd = fminf(dist[k], d);
      dist[k] = nd;
      if (nd > best) { best = nd; bidx = (uint32_t)(p0 + k * NTHR); }
    }

    // packed key: [tag:13 | dist_bits:32 | inv_idx:19]; max() == argmax w/
    // first-occurrence tie-break (smaller idx wins via inverted low bits).
    unsigned long long pk =
        ((unsigned long long)(uint32_t)(i + 1) << 51) |
        ((unsigned long long)__float_as_uint(best) << 19) |
        (unsigned long long)(0x7FFFFu - bidx);

#pragma unroll
    for (int off = 32; off >= 1; off >>= 1) {
      unsigned long long o = __shfl_xor(pk, off);
      if (o > pk) pk = o;
    }
    if (lane == 0) lds_red[wave] = pk;
    __syncthreads();

    unsigned long long* myslot = &slots[((size_t)(i & 1) * NB + b) * WPB];
    if (tid == 0) {
      unsigned long long m = lds_red[0];
#pragma unroll
      for (int q = 1; q < NTHR / 64; ++q)
        if (lds_red[q] > m) m = lds_red[q];
      __hip_atomic_store(&myslot[w], m, __ATOMIC_RELAXED,
                         __HIP_MEMORY_SCOPE_AGENT);
    }
    // wave 0 polls the batch's 16 slots (one 128B line) for this iter's tag
    if (wave == 0) {
      unsigned long long v = 0;
      if (lane < WPB) {
        const uint32_t tag = (uint32_t)(i + 1);
        do {
          v = __hip_atomic_load(&myslot[lane], __ATOMIC_RELAXED,
                                __HIP_MEMORY_SCOPE_AGENT);
        } while ((uint32_t)(v >> 51) != tag);
      }
#pragma unroll
      for (int off = 8; off >= 1; off >>= 1) {
        unsigned long long o = __shfl_xor(v, off);
        if (o > v) v = o;
      }
      if (lane == 0) lds_win = v;
    }
    __syncthreads();
    far = 0x7FFFFu - (uint32_t)(lds_win & 0x7FFFFu);
  }
}

extern "C" void kernel_launch(void* const* d_in, const int* in_sizes, int n_in,
                              void* d_out, int out_size, void* d_ws, size_t ws_size,
                              hipStream_t stream) {
  const float* xyz = (const float*)d_in[0];
  const int* npoint = (const int*)d_in[1];
  int N = in_sizes[0] / (NB * 3);  // 131072

  // zero the slot arrays (2 parities x NB x WPB u64 = 4 KiB)
  hipMemsetAsync(d_ws, 0, (size_t)2 * NB * WPB * sizeof(unsigned long long),
                 stream);
  FPSampler_42099269435595_kernel<<<NB * WPB, NTHR, 0, stream>>>(
      xyz, npoint, (float*)d_out, (unsigned long long*)d_ws, N);
}